// Round 1
// baseline (6176.662 us; speedup 1.0000x reference)
//
#include <hip/hip_runtime.h>
#include <hip/hip_bf16.h>
#include <stdint.h>

// Problem constants: E=1e6 edges (d0=64), N=1e5 nodes, d1=128 outputs.
// Output = segsum(relu(BN(concat(h1[src],m)@W0^T + b0)), dst)  [N,128]
// Split: x[e] = A[src[e]] + B[e],  A = h1@Wa^T + b0 (N rows), B = m@Wb^T (E rows)

#define TE 64      // rows per GEMM tile
#define LDW 68     // LDS row stride (floats): 68%32=4 -> conflict-light

__device__ inline uint16_t f2bf(float x) {
    uint32_t u = __float_as_uint(x);
    return (uint16_t)((u + 0x7fffu + ((u >> 16) & 1u)) >> 16);  // RNE
}
__device__ inline float bf2f(uint32_t lo16) { return __uint_as_float(lo16 << 16); }

// ---------------- K1: h1[dst[e]] += m[e]  (atomics) ----------------
__global__ __launch_bounds__(256) void k1_scatter_h1(
    const float* __restrict__ m, const int* __restrict__ dst,
    float* __restrict__ h1, int E)
{
    int tid = blockIdx.x * 256 + threadIdx.x;
    int e = tid >> 4, g = tid & 15;            // 16 threads/edge, float4 each
    if (e >= E) return;
    float4 v = ((const float4*)(m + (size_t)e * 64))[g];
    int d = dst[e];
    float* p = h1 + (size_t)d * 64 + g * 4;
    atomicAdd(p + 0, v.x); atomicAdd(p + 1, v.y);
    atomicAdd(p + 2, v.z); atomicAdd(p + 3, v.w);
}

// ---------------- K2/K3: tiled GEMM [R,64]@[64,128] ----------------
// EDGE=false: out fp32 A = X@Wa^T + b0  (row guard for R=N)
// EDGE=true : B = X@Wb^T; x = B + A[src]; stats sum/sumsq; store x as bf16
template<bool EDGE>
__global__ __launch_bounds__(256) void gemm_k(
    const float* __restrict__ X,        // [R,64]
    const float* __restrict__ W0,       // [128,128] row-major
    int wcol,                           // 0 (Wa) or 64 (Wb)
    const float* __restrict__ bias,     // b0 (A-mode) or null
    const float* __restrict__ A,        // gather src (EDGE)
    const int*   __restrict__ src,      // EDGE
    float* __restrict__ outA,           // A-mode output
    uint16_t* __restrict__ xbf,         // EDGE output (bf16 bits)
    float* __restrict__ gstats,         // EDGE: [0..127]=sum, [128..255]=sumsq
    int R, int ntiles)
{
    __shared__ float Wl[128 * LDW];     // 34.8 KB
    __shared__ float Ml[TE * LDW];      // 17.4 KB (reused as bf16 staging in EDGE)
    const int t  = threadIdx.x;
    const int te = t & 15;              // edge-group (lane&15)
    const int tj = t >> 4;              // j-group 0..15 (uniform per 16-lane group)

    // Load W columns [wcol..wcol+63] into LDS
    for (int idx = t; idx < 128 * 16; idx += 256) {
        int j = idx >> 4, k4 = idx & 15;
        float4 w = *(const float4*)(W0 + j * 128 + wcol + k4 * 4);
        *(float4*)(Wl + j * LDW + k4 * 4) = w;
    }

    float lsum[8], lsq[8];
    if (EDGE) {
        #pragma unroll
        for (int jj = 0; jj < 8; jj++) { lsum[jj] = 0.f; lsq[jj] = 0.f; }
    }

    for (int tile = blockIdx.x; tile < ntiles; tile += gridDim.x) {
        const int r0 = tile * TE;
        __syncthreads();                              // Ml safe to overwrite
        for (int idx = t; idx < TE * 16; idx += 256) {
            int e = idx >> 4, k4 = idx & 15;
            int r = r0 + e;
            float4 v = make_float4(0.f, 0.f, 0.f, 0.f);
            if (EDGE || r < R) v = *(const float4*)(X + (size_t)r * 64 + k4 * 4);
            *(float4*)(Ml + e * LDW + k4 * 4) = v;
        }
        __syncthreads();

        float acc[4][8];
        #pragma unroll
        for (int i = 0; i < 4; i++)
            #pragma unroll
            for (int jj = 0; jj < 8; jj++) acc[i][jj] = 0.f;

        #pragma unroll
        for (int k = 0; k < 64; k += 4) {
            float4 mv[4], wv[8];
            #pragma unroll
            for (int i = 0; i < 4; i++)
                mv[i] = *(const float4*)(Ml + (te + 16 * i) * LDW + k);
            #pragma unroll
            for (int jj = 0; jj < 8; jj++)
                wv[jj] = *(const float4*)(Wl + (tj + 16 * jj) * LDW + k);
            #pragma unroll
            for (int i = 0; i < 4; i++)
                #pragma unroll
                for (int jj = 0; jj < 8; jj++)
                    acc[i][jj] += mv[i].x * wv[jj].x + mv[i].y * wv[jj].y
                                + mv[i].z * wv[jj].z + mv[i].w * wv[jj].w;
        }

        if (!EDGE) {
            #pragma unroll
            for (int i = 0; i < 4; i++) {
                int r = r0 + te + 16 * i;
                if (r < R) {
                    #pragma unroll
                    for (int jj = 0; jj < 8; jj++) {
                        int j = tj + 16 * jj;
                        outA[(size_t)r * 128 + j] = acc[i][jj] + bias[j];
                    }
                }
            }
        } else {
            __syncthreads();                          // done reading Ml
            uint16_t* xs = (uint16_t*)Ml;             // staging [64][132] bf16
            #pragma unroll
            for (int i = 0; i < 4; i++) {
                int el = te + 16 * i;
                int e  = r0 + el;
                const float* Ar = A + (size_t)src[e] * 128;
                #pragma unroll
                for (int jj = 0; jj < 8; jj++) {
                    int j = tj + 16 * jj;
                    float x = acc[i][jj] + Ar[j];
                    lsum[jj] += x;
                    lsq[jj]  += x * x;
                    xs[el * 132 + j] = f2bf(x);
                }
            }
            __syncthreads();
            // coalesced store: rows viewed as 66 uints, first 64 = 128 bf16
            const uint32_t* xsu = (const uint32_t*)Ml;
            uint32_t* outu = (uint32_t*)(xbf + (size_t)r0 * 128);
            for (int idx = t; idx < TE * 64; idx += 256) {
                int e = idx >> 6, seg = idx & 63;
                outu[e * 64 + seg] = xsu[e * 66 + seg];
            }
        }
    }

    if (EDGE) {
        // reduce over the 16-lane group (same tj), then one atomic set per group
        #pragma unroll
        for (int o = 8; o >= 1; o >>= 1) {
            #pragma unroll
            for (int jj = 0; jj < 8; jj++) {
                lsum[jj] += __shfl_xor(lsum[jj], o, 16);
                lsq[jj]  += __shfl_xor(lsq[jj],  o, 16);
            }
        }
        if (te == 0) {
            #pragma unroll
            for (int jj = 0; jj < 8; jj++) {
                int j = tj + 16 * jj;
                atomicAdd(gstats + j,        lsum[jj]);
                atomicAdd(gstats + 128 + j,  lsq[jj]);
            }
        }
    }
}

// ---------------- K4: finalize BN scale/shift ----------------
__global__ void k4_finalize(const float* __restrict__ gstats,
                            const float* __restrict__ g0,
                            const float* __restrict__ beta0,
                            float* __restrict__ sc, float Einv)
{
    int j = threadIdx.x;   // 128 threads
    float mu  = gstats[j] * Einv;
    float var = gstats[128 + j] * Einv - mu * mu;
    float s   = g0[j] * rsqrtf(var + 1e-5f);
    sc[j]       = s;
    sc[128 + j] = beta0[j] - mu * s;
}

// ---------------- K5: out[dst[e]] += relu(x*scale+shift) ----------------
__global__ __launch_bounds__(256) void k5_scatter_out(
    const uint16_t* __restrict__ xbf, const int* __restrict__ dst,
    const float* __restrict__ sc, float* __restrict__ out, int E)
{
    __shared__ float s_sc[256];
    s_sc[threadIdx.x] = sc[threadIdx.x];
    __syncthreads();
    int tid = blockIdx.x * 256 + threadIdx.x;
    int e = tid >> 4, h = tid & 15;            // 16 threads/edge, 8 bf16 each
    if (e >= E) return;
    uint4 raw = *(const uint4*)(xbf + (size_t)e * 128 + h * 8);
    int d = dst[e];
    float* op = out + (size_t)d * 128 + h * 8;
    const uint32_t* rw = (const uint32_t*)&raw;
    #pragma unroll
    for (int q = 0; q < 4; q++) {
        uint32_t pair = rw[q];
        int j0 = h * 8 + q * 2;
        float y0 = fmaxf(bf2f(pair & 0xffffu) * s_sc[j0]     + s_sc[128 + j0],     0.f);
        float y1 = fmaxf(bf2f(pair >> 16)     * s_sc[j0 + 1] + s_sc[128 + j0 + 1], 0.f);
        atomicAdd(op + q * 2,     y0);
        atomicAdd(op + q * 2 + 1, y1);
    }
}

extern "C" void kernel_launch(void* const* d_in, const int* in_sizes, int n_in,
                              void* d_out, int out_size, void* d_ws, size_t ws_size,
                              hipStream_t stream)
{
    const float* m     = (const float*)d_in[0];
    const float* W0    = (const float*)d_in[1];
    const float* b0    = (const float*)d_in[2];
    const float* g0    = (const float*)d_in[3];
    const float* beta0 = (const float*)d_in[4];
    const int*   src   = (const int*)d_in[9];
    const int*   dst   = (const int*)d_in[10];
    float* out = (float*)d_out;

    const int E = in_sizes[0] / 64;     // 1,000,000
    const int N = out_size / 128;       // 100,000

    // workspace layout (256B aligned)
    auto align = [](size_t x) { return (x + 255) & ~(size_t)255; };
    char* ws = (char*)d_ws;
    size_t o_h1 = 0;
    size_t o_A  = align(o_h1 + (size_t)N * 64 * 4);
    size_t o_x  = align(o_A  + (size_t)N * 128 * 4);
    size_t o_gs = align(o_x  + (size_t)E * 128 * 2);
    size_t o_sc = align(o_gs + 256 * 4);
    float*    h1  = (float*)(ws + o_h1);
    float*    A   = (float*)(ws + o_A);
    uint16_t* xbf = (uint16_t*)(ws + o_x);
    float*    gs  = (float*)(ws + o_gs);
    float*    sc  = (float*)(ws + o_sc);

    hipMemsetAsync(h1, 0, (size_t)N * 64 * 4, stream);
    hipMemsetAsync(gs, 0, 256 * 4, stream);
    hipMemsetAsync(out, 0, (size_t)N * 128 * 4, stream);

    // K1: h1 = segsum(m, dst)
    k1_scatter_h1<<<(E * 16 + 255) / 256, 256, 0, stream>>>(m, dst, h1, E);

    // K2: A = h1 @ Wa^T + b0
    int ntA = (N + TE - 1) / TE;
    gemm_k<false><<<ntA, 256, 0, stream>>>(h1, W0, 0, b0, nullptr, nullptr,
                                           A, nullptr, nullptr, N, ntA);

    // K3: x = m @ Wb^T + A[src]; stats; store bf16
    int ntE = E / TE;
    gemm_k<true><<<2048, 256, 0, stream>>>(m, W0, 64, nullptr, A, src,
                                           nullptr, xbf, gs, E, ntE);

    // K4: scale/shift
    k4_finalize<<<1, 128, 0, stream>>>(gs, g0, beta0, sc, 1.0f / (float)E);

    // K5: out = segsum(relu(x*scale+shift), dst)
    k5_scatter_out<<<(E * 16 + 255) / 256, 256, 0, stream>>>(xbf, dst, sc, out, E);
}

// Round 2
// 2448.583 us; speedup vs baseline: 2.5225x; 2.5225x over previous
//
#include <hip/hip_runtime.h>
#include <hip/hip_bf16.h>
#include <stdint.h>

// E=1e6 edges (d0=64), N=1e5 nodes, d1=128.
// out = segsum(relu(BN(concat(h1[src],m)@W0^T + b0)), dst)  [N,128]
// Split: x[e] = A[src[e]] + B[e],  A = h1@Wa^T + b0 (N rows), B = m@Wb^T (E rows)
// R2: counting-sort edges by dst; both segment-sums become gathers (no fp32 atomics).

#define TE 64      // rows per GEMM tile
#define LDW 68     // LDS row stride (floats)

__device__ inline uint16_t f2bf(float x) {
    uint32_t u = __float_as_uint(x);
    return (uint16_t)((u + 0x7fffu + ((u >> 16) & 1u)) >> 16);  // RNE
}
__device__ inline float bf2f(uint32_t lo16) { return __uint_as_float(lo16 << 16); }

// ---------------- sort: histogram ----------------
__global__ __launch_bounds__(256) void k_hist(const int* __restrict__ dst,
                                              int* __restrict__ cnt, int E)
{
    int e = blockIdx.x * 256 + threadIdx.x;
    if (e < E) atomicAdd(&cnt[dst[e]], 1);
}

// ---------------- sort: exclusive scan (single block, 1024 thr) ----------------
__global__ __launch_bounds__(1024) void k_scan(const int* __restrict__ cnt,
                                               int* __restrict__ off,
                                               int* __restrict__ cur, int N)
{
    __shared__ int wsum[16];
    __shared__ int carry;
    const int lane = threadIdx.x & 63, wid = threadIdx.x >> 6;
    if (threadIdx.x == 0) carry = 0;
    __syncthreads();
    for (int base = 0; base < N; base += 1024) {
        int i = base + (int)threadIdx.x;
        int v = (i < N) ? cnt[i] : 0;
        int x = v;
        #pragma unroll
        for (int o = 1; o < 64; o <<= 1) {
            int y = __shfl_up(x, o, 64);
            if (lane >= o) x += y;
        }
        if (lane == 63) wsum[wid] = x;
        __syncthreads();
        if (wid == 0) {
            int t = (lane < 16) ? wsum[lane] : 0;
            #pragma unroll
            for (int o = 1; o < 16; o <<= 1) {
                int y = __shfl_up(t, o, 64);
                if (lane >= o) t += y;
            }
            if (lane < 16) wsum[lane] = t;
        }
        __syncthreads();
        int wbase = (wid == 0) ? 0 : wsum[wid - 1];
        int excl = carry + wbase + x - v;
        if (i < N) { off[i] = excl; cur[i] = excl; }
        __syncthreads();
        if (threadIdx.x == 1023) carry += wsum[15];
        __syncthreads();
    }
}

// ---------------- sort: fill permutation ----------------
__global__ __launch_bounds__(256) void k_perm(const int* __restrict__ dst,
                                              int* __restrict__ cur,
                                              int* __restrict__ perm, int E)
{
    int e = blockIdx.x * 256 + threadIdx.x;
    if (e < E) {
        int pos = atomicAdd(&cur[dst[e]], 1);
        perm[pos] = e;
    }
}

// ---------------- K1: h1[n] = sum of m rows of n's edges (gather) ----------------
__global__ __launch_bounds__(256) void k1_gather_h1(
    const float* __restrict__ m, const int* __restrict__ perm,
    const int* __restrict__ off, const int* __restrict__ cur,
    float* __restrict__ h1, int N)
{
    const int lane = threadIdx.x & 63;
    const int n = blockIdx.x * 4 + (threadIdx.x >> 6);
    if (n >= N) return;
    const int s0 = off[n], s1 = cur[n];     // cur ended at segment end
    float acc = 0.f;
    for (int i = s0; i < s1; i++) {
        int e = perm[i];
        acc += m[(size_t)e * 64 + lane];
    }
    h1[(size_t)n * 64 + lane] = acc;
}

// ---------------- K2/K3: tiled GEMM [R,64]@[64,128] ----------------
template<bool EDGE>
__global__ __launch_bounds__(256) void gemm_k(
    const float* __restrict__ X,        // [R,64]
    const float* __restrict__ W0,       // [128,128] row-major
    int wcol,                           // 0 (Wa) or 64 (Wb)
    const float* __restrict__ bias,     // b0 (A-mode) or null
    const float* __restrict__ A,        // gather src (EDGE)
    const int*   __restrict__ src,      // EDGE
    float* __restrict__ outA,           // A-mode output
    uint16_t* __restrict__ xbf,         // EDGE output (bf16 bits)
    float* __restrict__ gstats,         // EDGE: [0..127]=sum, [128..255]=sumsq
    int R, int ntiles)
{
    __shared__ float Wl[128 * LDW];
    __shared__ float Ml[TE * LDW];
    const int t  = threadIdx.x;
    const int te = t & 15;
    const int tj = t >> 4;

    for (int idx = t; idx < 128 * 16; idx += 256) {
        int j = idx >> 4, k4 = idx & 15;
        float4 w = *(const float4*)(W0 + j * 128 + wcol + k4 * 4);
        *(float4*)(Wl + j * LDW + k4 * 4) = w;
    }

    float lsum[8], lsq[8];
    if (EDGE) {
        #pragma unroll
        for (int jj = 0; jj < 8; jj++) { lsum[jj] = 0.f; lsq[jj] = 0.f; }
    }

    for (int tile = blockIdx.x; tile < ntiles; tile += gridDim.x) {
        const int r0 = tile * TE;
        __syncthreads();
        for (int idx = t; idx < TE * 16; idx += 256) {
            int e = idx >> 4, k4 = idx & 15;
            int r = r0 + e;
            float4 v = make_float4(0.f, 0.f, 0.f, 0.f);
            if (EDGE || r < R) v = *(const float4*)(X + (size_t)r * 64 + k4 * 4);
            *(float4*)(Ml + e * LDW + k4 * 4) = v;
        }
        __syncthreads();

        float acc[4][8];
        #pragma unroll
        for (int i = 0; i < 4; i++)
            #pragma unroll
            for (int jj = 0; jj < 8; jj++) acc[i][jj] = 0.f;

        #pragma unroll
        for (int k = 0; k < 64; k += 4) {
            float4 mv[4], wv[8];
            #pragma unroll
            for (int i = 0; i < 4; i++)
                mv[i] = *(const float4*)(Ml + (te + 16 * i) * LDW + k);
            #pragma unroll
            for (int jj = 0; jj < 8; jj++)
                wv[jj] = *(const float4*)(Wl + (tj + 16 * jj) * LDW + k);
            #pragma unroll
            for (int i = 0; i < 4; i++)
                #pragma unroll
                for (int jj = 0; jj < 8; jj++)
                    acc[i][jj] += mv[i].x * wv[jj].x + mv[i].y * wv[jj].y
                                + mv[i].z * wv[jj].z + mv[i].w * wv[jj].w;
        }

        if (!EDGE) {
            #pragma unroll
            for (int i = 0; i < 4; i++) {
                int r = r0 + te + 16 * i;
                if (r < R) {
                    #pragma unroll
                    for (int jj = 0; jj < 8; jj++) {
                        int j = tj + 16 * jj;
                        outA[(size_t)r * 128 + j] = acc[i][jj] + bias[j];
                    }
                }
            }
        } else {
            __syncthreads();
            uint16_t* xs = (uint16_t*)Ml;             // staging [64][132] bf16
            #pragma unroll
            for (int i = 0; i < 4; i++) {
                int el = te + 16 * i;
                int e  = r0 + el;
                const float* Ar = A + (size_t)src[e] * 128;
                #pragma unroll
                for (int jj = 0; jj < 8; jj++) {
                    int j = tj + 16 * jj;
                    float x = acc[i][jj] + Ar[j];
                    lsum[jj] += x;
                    lsq[jj]  += x * x;
                    xs[el * 132 + j] = f2bf(x);
                }
            }
            __syncthreads();
            const uint32_t* xsu = (const uint32_t*)Ml;
            uint32_t* outu = (uint32_t*)(xbf + (size_t)r0 * 128);
            for (int idx = t; idx < TE * 64; idx += 256) {
                int e = idx >> 6, seg = idx & 63;
                outu[e * 64 + seg] = xsu[e * 66 + seg];
            }
        }
    }

    if (EDGE) {
        #pragma unroll
        for (int o = 8; o >= 1; o >>= 1) {
            #pragma unroll
            for (int jj = 0; jj < 8; jj++) {
                lsum[jj] += __shfl_xor(lsum[jj], o, 16);
                lsq[jj]  += __shfl_xor(lsq[jj],  o, 16);
            }
        }
        if (te == 0) {
            #pragma unroll
            for (int jj = 0; jj < 8; jj++) {
                int j = tj + 16 * jj;
                atomicAdd(gstats + j,        lsum[jj]);
                atomicAdd(gstats + 128 + j,  lsq[jj]);
            }
        }
    }
}

// ---------------- K4: finalize BN scale/shift ----------------
__global__ void k4_finalize(const float* __restrict__ gstats,
                            const float* __restrict__ g0,
                            const float* __restrict__ beta0,
                            float* __restrict__ sc, float Einv)
{
    int j = threadIdx.x;   // 128 threads
    float mu  = gstats[j] * Einv;
    float var = gstats[128 + j] * Einv - mu * mu;
    float s   = g0[j] * rsqrtf(var + 1e-5f);
    sc[j]       = s;
    sc[128 + j] = beta0[j] - mu * s;
}

// ---------------- K5: out[n] = sum relu(x*scale+shift) over n's edges ----------------
__global__ __launch_bounds__(256) void k5_gather_out(
    const uint16_t* __restrict__ xbf, const int* __restrict__ perm,
    const int* __restrict__ off, const int* __restrict__ cur,
    const float* __restrict__ sc, float* __restrict__ out, int N)
{
    const int lane = threadIdx.x & 63;
    const int n = blockIdx.x * 4 + (threadIdx.x >> 6);
    if (n >= N) return;
    float2 s = ((const float2*)sc)[lane];          // scale for cols 2l,2l+1
    float2 b = ((const float2*)(sc + 128))[lane];  // shift
    const int s0 = off[n], s1 = cur[n];
    float a0 = 0.f, a1 = 0.f;
    for (int i = s0; i < s1; i++) {
        int e = perm[i];
        uint32_t pair = *(const uint32_t*)(xbf + (size_t)e * 128 + 2 * lane);
        a0 += fmaxf(bf2f(pair & 0xffffu) * s.x + b.x, 0.f);
        a1 += fmaxf(bf2f(pair >> 16)     * s.y + b.y, 0.f);
    }
    ((float2*)(out + (size_t)n * 128))[lane] = make_float2(a0, a1);
}

extern "C" void kernel_launch(void* const* d_in, const int* in_sizes, int n_in,
                              void* d_out, int out_size, void* d_ws, size_t ws_size,
                              hipStream_t stream)
{
    const float* m     = (const float*)d_in[0];
    const float* W0    = (const float*)d_in[1];
    const float* b0    = (const float*)d_in[2];
    const float* g0    = (const float*)d_in[3];
    const float* beta0 = (const float*)d_in[4];
    const int*   src   = (const int*)d_in[9];
    const int*   dst   = (const int*)d_in[10];
    float* out = (float*)d_out;

    const int E = in_sizes[0] / 64;     // 1,000,000
    const int N = out_size / 128;       // 100,000

    auto align = [](size_t x) { return (x + 255) & ~(size_t)255; };
    char* ws = (char*)d_ws;
    size_t o_h1  = 0;
    size_t o_A   = align(o_h1 + (size_t)N * 64 * 4);
    size_t o_x   = align(o_A  + (size_t)N * 128 * 4);
    size_t o_gs  = align(o_x  + (size_t)E * 128 * 2);
    size_t o_sc  = align(o_gs + 256 * 4);
    size_t o_cnt = align(o_sc + 256 * 4);
    size_t o_off = align(o_cnt + (size_t)N * 4);
    size_t o_cur = align(o_off + (size_t)N * 4);
    size_t o_pm  = align(o_cur + (size_t)N * 4);
    float*    h1   = (float*)(ws + o_h1);
    float*    A    = (float*)(ws + o_A);
    uint16_t* xbf  = (uint16_t*)(ws + o_x);
    float*    gs   = (float*)(ws + o_gs);
    float*    sc   = (float*)(ws + o_sc);
    int*      cnt  = (int*)(ws + o_cnt);
    int*      off  = (int*)(ws + o_off);
    int*      cur  = (int*)(ws + o_cur);
    int*      perm = (int*)(ws + o_pm);

    hipMemsetAsync(cnt, 0, (size_t)N * 4, stream);
    hipMemsetAsync(gs, 0, 256 * 4, stream);

    // ---- counting sort by dst ----
    k_hist<<<(E + 255) / 256, 256, 0, stream>>>(dst, cnt, E);
    k_scan<<<1, 1024, 0, stream>>>(cnt, off, cur, N);
    k_perm<<<(E + 255) / 256, 256, 0, stream>>>(dst, cur, perm, E);
    // after k_perm: cur[n] == segment end for node n

    // K1: h1 = segsum(m, dst) via gather
    k1_gather_h1<<<(N + 3) / 4, 256, 0, stream>>>(m, perm, off, cur, h1, N);

    // K2: A = h1 @ Wa^T + b0
    int ntA = (N + TE - 1) / TE;
    gemm_k<false><<<ntA, 256, 0, stream>>>(h1, W0, 0, b0, nullptr, nullptr,
                                           A, nullptr, nullptr, N, ntA);

    // K3: x = m @ Wb^T + A[src]; stats; store bf16
    int ntE = E / TE;
    gemm_k<true><<<2048, 256, 0, stream>>>(m, W0, 64, nullptr, A, src,
                                           nullptr, xbf, gs, E, ntE);

    // K4: scale/shift
    k4_finalize<<<1, 128, 0, stream>>>(gs, g0, beta0, sc, 1.0f / (float)E);

    // K5: out = segsum(relu(x*scale+shift), dst) via gather
    k5_gather_out<<<(N + 3) / 4, 256, 0, stream>>>(xbf, perm, off, cur, sc, out, N);
}

// Round 3
// 969.757 us; speedup vs baseline: 6.3693x; 2.5249x over previous
//
#include <hip/hip_runtime.h>
#include <hip/hip_bf16.h>
#include <stdint.h>

// E=1e6 edges (d0=64), N=1e5 nodes, d1=128.
// out = segsum(relu(BN(concat(h1[src],m)@W0^T + b0)), dst)  [N,128]
// Split: x[e] = A[src[e]] + B[e],  A = h1@Wa^T + b0 (N rows), B = m@Wb^T (E rows)
// R3: MFMA bf16 GEMM, no LDS staging (a-frags load coalesced straight from global);
//     multi-block scan; h1 kept as bf16.

typedef __attribute__((ext_vector_type(8))) short bf16x8;
typedef __attribute__((ext_vector_type(4))) float f32x4;

__device__ inline uint16_t f2bf(float x) {
    uint32_t u = __float_as_uint(x);
    return (uint16_t)((u + 0x7fffu + ((u >> 16) & 1u)) >> 16);  // RNE
}
__device__ inline float bf2f(uint32_t lo16) { return __uint_as_float(lo16 << 16); }

// ---------------- sort: histogram ----------------
__global__ __launch_bounds__(256) void k_hist(const int* __restrict__ dst,
                                              int* __restrict__ cnt, int E)
{
    int e = blockIdx.x * 256 + threadIdx.x;
    if (e < E) atomicAdd(&cnt[dst[e]], 1);
}

// ---------------- scan A: per-block (1024 elems) sums ----------------
__global__ __launch_bounds__(256) void k_scanA(const int* __restrict__ cnt,
                                               int* __restrict__ bsum, int N)
{
    int t = threadIdx.x, b = blockIdx.x;
    int i4 = b * 256 + t;
    int4 v = make_int4(0, 0, 0, 0);
    if (i4 < (N >> 2)) v = ((const int4*)cnt)[i4];
    int s = v.x + v.y + v.z + v.w;
    #pragma unroll
    for (int o = 1; o < 64; o <<= 1) s += __shfl_xor(s, o, 64);
    __shared__ int ws[4];
    if ((t & 63) == 0) ws[t >> 6] = s;
    __syncthreads();
    if (t == 0) bsum[b] = ws[0] + ws[1] + ws[2] + ws[3];
}

// ---------------- scan B: exclusive scan of block sums (nb<=128) ----------------
__global__ __launch_bounds__(128) void k_scanB(int* __restrict__ bsum, int nb)
{
    int t = threadIdx.x;
    int v = (t < nb) ? bsum[t] : 0;
    int lane = t & 63, w = t >> 6;
    int x = v;
    #pragma unroll
    for (int o = 1; o < 64; o <<= 1) {
        int y = __shfl_up(x, o, 64);
        if (lane >= o) x += y;
    }
    __shared__ int wt[2];
    if (lane == 63) wt[w] = x;
    __syncthreads();
    if (w == 1) x += wt[0];
    if (t < nb) bsum[t] = x - v;   // exclusive
}

// ---------------- scan C: write off/cur ----------------
__global__ __launch_bounds__(256) void k_scanC(const int* __restrict__ cnt,
                                               const int* __restrict__ bsum,
                                               int* __restrict__ off,
                                               int* __restrict__ cur, int N)
{
    int t = threadIdx.x, b = blockIdx.x;
    int i4 = b * 256 + t;
    bool ok = (i4 < (N >> 2));
    int4 v = make_int4(0, 0, 0, 0);
    if (ok) v = ((const int4*)cnt)[i4];
    int s = v.x + v.y + v.z + v.w;
    int lane = t & 63, w = t >> 6;
    int x = s;
    #pragma unroll
    for (int o = 1; o < 64; o <<= 1) {
        int y = __shfl_up(x, o, 64);
        if (lane >= o) x += y;
    }
    __shared__ int wt[4];
    if (lane == 63) wt[w] = x;
    __syncthreads();
    int wbase = 0;
    for (int k = 0; k < w; k++) wbase += wt[k];
    int excl = bsum[b] + wbase + x - s;
    if (ok) {
        int4 o4;
        o4.x = excl; o4.y = excl + v.x; o4.z = o4.y + v.y; o4.w = o4.z + v.z;
        ((int4*)off)[i4] = o4;
        ((int4*)cur)[i4] = o4;
    }
}

// ---------------- sort: fill permutation ----------------
__global__ __launch_bounds__(256) void k_perm(const int* __restrict__ dst,
                                              int* __restrict__ cur,
                                              int* __restrict__ perm, int E)
{
    int e = blockIdx.x * 256 + threadIdx.x;
    if (e < E) {
        int pos = atomicAdd(&cur[dst[e]], 1);
        perm[pos] = e;
    }
}

// ---------------- K1: h1bf[n] = bf16(sum of m rows of n's edges) ----------------
__global__ __launch_bounds__(256) void k1_gather_h1(
    const float* __restrict__ m, const int* __restrict__ perm,
    const int* __restrict__ off, const int* __restrict__ cur,
    ushort* __restrict__ h1bf, int N)
{
    const int lane = threadIdx.x & 63;
    const int n = blockIdx.x * 4 + (threadIdx.x >> 6);
    if (n >= N) return;
    const int s0 = off[n], s1 = cur[n];
    float acc = 0.f;
    for (int i = s0; i < s1; i++) {
        int e = perm[i];
        acc += m[(size_t)e * 64 + lane];
    }
    h1bf[(size_t)n * 64 + lane] = f2bf(acc);
}

// ---------------- K2/K3: MFMA GEMM [R,64]@[64,128], no LDS staging ----------------
// a-frag: A[m=lane&15][k=quad*8+j]  -> one 16B load per lane per k-step, coalesced
// b-frag: B[k=quad*8+j][n=lane&15]  -> W0[n][wcol+k], register-resident (16 frags)
// C/D   : col=lane&15, row=quad*4+reg   (m89-verified)
template<bool EDGE>
__global__ __launch_bounds__(256) void gemm_mfma(
    const void* __restrict__ Xv,        // EDGE: float* m [E,64]; else ushort* h1bf [Npad,64]
    const float* __restrict__ W0,       // [128,128] row-major
    int wcol,                           // 0 (Wa) or 64 (Wb)
    const float* __restrict__ bias,     // !EDGE: b0
    const float* __restrict__ A,        // EDGE: gather table [N,128]
    const int*   __restrict__ src,      // EDGE
    float* __restrict__ outA,           // !EDGE output
    ushort* __restrict__ xbf,           // EDGE output bf16
    float* __restrict__ gstats,         // EDGE: [0..127]=sum, [128..255]=sumsq
    int R, int ntiles)
{
    const int t  = threadIdx.x;
    const int l  = t & 63;
    const int lm = l & 15;              // m/n index within 16
    const int q  = l >> 4;              // quad 0..3
    const int wv = t >> 6;              // wave 0..3

    // ---- register-resident B fragments (bf16) ----
    bf16x8 bfr[8][2];
    #pragma unroll
    for (int nt = 0; nt < 8; nt++)
        #pragma unroll
        for (int ks = 0; ks < 2; ks++) {
            const float* wp = W0 + (nt * 16 + lm) * 128 + wcol + ks * 32 + q * 8;
            bf16x8 bf;
            #pragma unroll
            for (int j = 0; j < 8; j++) ((ushort*)&bf)[j] = f2bf(wp[j]);
            bfr[nt][ks] = bf;
        }
    float bs[8];
    if (!EDGE) {
        #pragma unroll
        for (int nt = 0; nt < 8; nt++) bs[nt] = bias[nt * 16 + lm];
    }

    __shared__ float sst[256];
    float lsum[8], lsq[8];
    if (EDGE) {
        #pragma unroll
        for (int nt = 0; nt < 8; nt++) { lsum[nt] = 0.f; lsq[nt] = 0.f; }
        sst[t] = 0.f;
        __syncthreads();
    }

    for (int tile = blockIdx.x; tile < ntiles; tile += gridDim.x) {
        const int r0 = tile * 64 + wv * 16;      // this wave's 16 rows

        // ---- a-fragments straight from global ----
        bf16x8 af[2];
        if (EDGE) {
            const float* xp = (const float*)Xv + (size_t)(r0 + lm) * 64 + q * 8;
            #pragma unroll
            for (int ks = 0; ks < 2; ks++) {
                float4 w0 = *(const float4*)(xp + ks * 32);
                float4 w1 = *(const float4*)(xp + ks * 32 + 4);
                bf16x8 bf;
                ((ushort*)&bf)[0] = f2bf(w0.x); ((ushort*)&bf)[1] = f2bf(w0.y);
                ((ushort*)&bf)[2] = f2bf(w0.z); ((ushort*)&bf)[3] = f2bf(w0.w);
                ((ushort*)&bf)[4] = f2bf(w1.x); ((ushort*)&bf)[5] = f2bf(w1.y);
                ((ushort*)&bf)[6] = f2bf(w1.z); ((ushort*)&bf)[7] = f2bf(w1.w);
                af[ks] = bf;
            }
        } else {
            const ushort* xp = (const ushort*)Xv + (size_t)(r0 + lm) * 64 + q * 8;
            af[0] = *(const bf16x8*)xp;
            af[1] = *(const bf16x8*)(xp + 32);
        }

        f32x4 acc[8];
        #pragma unroll
        for (int nt = 0; nt < 8; nt++) acc[nt] = (f32x4){0.f, 0.f, 0.f, 0.f};
        #pragma unroll
        for (int ks = 0; ks < 2; ks++)
            #pragma unroll
            for (int nt = 0; nt < 8; nt++)
                acc[nt] = __builtin_amdgcn_mfma_f32_16x16x32_bf16(
                              af[ks], bfr[nt][ks], acc[nt], 0, 0, 0);

        if (!EDGE) {
            #pragma unroll
            for (int r = 0; r < 4; r++) {
                int row = r0 + q * 4 + r;
                if (row < R) {
                    #pragma unroll
                    for (int nt = 0; nt < 8; nt++)
                        outA[(size_t)row * 128 + nt * 16 + lm] = acc[nt][r] + bs[nt];
                }
            }
        } else {
            int4 rA = *(const int4*)(src + r0 + q * 4);   // src for rows q*4..q*4+3
            const int* rAp = &rA.x;
            #pragma unroll
            for (int r = 0; r < 4; r++) {
                int row = r0 + q * 4 + r;
                const float* Ar = A + (size_t)rAp[r] * 128;
                ushort* xo = xbf + (size_t)row * 128 + lm;
                #pragma unroll
                for (int nt = 0; nt < 8; nt++) {
                    float y = acc[nt][r] + Ar[nt * 16 + lm];
                    lsum[nt] += y;
                    lsq[nt]  += y * y;
                    xo[nt * 16] = f2bf(y);
                }
            }
        }
    }

    if (EDGE) {
        // reduce stats across quads (lanes with same lm), then block LDS, then global
        #pragma unroll
        for (int nt = 0; nt < 8; nt++) {
            #pragma unroll
            for (int o = 16; o < 64; o <<= 1) {
                lsum[nt] += __shfl_xor(lsum[nt], o, 64);
                lsq[nt]  += __shfl_xor(lsq[nt],  o, 64);
            }
        }
        __syncthreads();
        if (l < 16) {
            #pragma unroll
            for (int nt = 0; nt < 8; nt++) {
                atomicAdd(&sst[nt * 16 + l],       lsum[nt]);
                atomicAdd(&sst[128 + nt * 16 + l], lsq[nt]);
            }
        }
        __syncthreads();
        atomicAdd(&gstats[t], sst[t]);
    }
}

// ---------------- K4: finalize BN scale/shift ----------------
__global__ void k4_finalize(const float* __restrict__ gstats,
                            const float* __restrict__ g0,
                            const float* __restrict__ beta0,
                            float* __restrict__ sc, float Einv)
{
    int j = threadIdx.x;   // 128 threads
    float mu  = gstats[j] * Einv;
    float var = gstats[128 + j] * Einv - mu * mu;
    float s   = g0[j] * rsqrtf(var + 1e-5f);
    sc[j]       = s;
    sc[128 + j] = beta0[j] - mu * s;
}

// ---------------- K5: out[n] = sum relu(x*scale+shift) over n's edges ----------------
__global__ __launch_bounds__(256) void k5_gather_out(
    const ushort* __restrict__ xbf, const int* __restrict__ perm,
    const int* __restrict__ off, const int* __restrict__ cur,
    const float* __restrict__ sc, float* __restrict__ out, int N)
{
    const int lane = threadIdx.x & 63;
    const int n = blockIdx.x * 4 + (threadIdx.x >> 6);
    if (n >= N) return;
    float2 s = ((const float2*)sc)[lane];
    float2 b = ((const float2*)(sc + 128))[lane];
    const int s0 = off[n], s1 = cur[n];
    float a0 = 0.f, a1 = 0.f;
    for (int i = s0; i < s1; i++) {
        int e = perm[i];
        uint32_t pair = *(const uint32_t*)(xbf + (size_t)e * 128 + 2 * lane);
        a0 += fmaxf(bf2f(pair & 0xffffu) * s.x + b.x, 0.f);
        a1 += fmaxf(bf2f(pair >> 16)     * s.y + b.y, 0.f);
    }
    ((float2*)(out + (size_t)n * 128))[lane] = make_float2(a0, a1);
}

extern "C" void kernel_launch(void* const* d_in, const int* in_sizes, int n_in,
                              void* d_out, int out_size, void* d_ws, size_t ws_size,
                              hipStream_t stream)
{
    const float* m     = (const float*)d_in[0];
    const float* W0    = (const float*)d_in[1];
    const float* b0    = (const float*)d_in[2];
    const float* g0    = (const float*)d_in[3];
    const float* beta0 = (const float*)d_in[4];
    const int*   src   = (const int*)d_in[9];
    const int*   dst   = (const int*)d_in[10];
    float* out = (float*)d_out;

    const int E = in_sizes[0] / 64;     // 1,000,000
    const int N = out_size / 128;       // 100,000
    const int ntA = (N + 63) / 64;      // 1563 tiles for A-GEMM
    const int Npad = ntA * 64;          // padded row count for h1bf
    const int ntE = E / 64;             // 15625 tiles
    const int nb  = (N + 1023) / 1024;  // scan blocks

    auto align = [](size_t x) { return (x + 255) & ~(size_t)255; };
    char* ws = (char*)d_ws;
    size_t o_h1  = 0;
    size_t o_A   = align(o_h1 + (size_t)Npad * 64 * 2);
    size_t o_x   = align(o_A  + (size_t)N * 128 * 4);
    size_t o_gs  = align(o_x  + (size_t)E * 128 * 2);
    size_t o_sc  = align(o_gs + 256 * 4);
    size_t o_cnt = align(o_sc + 256 * 4);
    size_t o_off = align(o_cnt + (size_t)N * 4);
    size_t o_cur = align(o_off + (size_t)N * 4);
    size_t o_pm  = align(o_cur + (size_t)N * 4);
    size_t o_bs  = align(o_pm  + (size_t)E * 4);
    ushort*   h1bf = (ushort*)(ws + o_h1);
    float*    A    = (float*)(ws + o_A);
    ushort*   xbf  = (ushort*)(ws + o_x);
    float*    gs   = (float*)(ws + o_gs);
    float*    sc   = (float*)(ws + o_sc);
    int*      cnt  = (int*)(ws + o_cnt);
    int*      off  = (int*)(ws + o_off);
    int*      cur  = (int*)(ws + o_cur);
    int*      perm = (int*)(ws + o_pm);
    int*      bsum = (int*)(ws + o_bs);

    hipMemsetAsync(cnt, 0, (size_t)N * 4, stream);
    hipMemsetAsync(gs, 0, 256 * 4, stream);

    // ---- counting sort by dst ----
    k_hist<<<(E + 255) / 256, 256, 0, stream>>>(dst, cnt, E);
    k_scanA<<<nb, 256, 0, stream>>>(cnt, bsum, N);
    k_scanB<<<1, 128, 0, stream>>>(bsum, nb);
    k_scanC<<<nb, 256, 0, stream>>>(cnt, bsum, off, cur, N);
    k_perm<<<(E + 255) / 256, 256, 0, stream>>>(dst, cur, perm, E);
    // after k_perm: cur[n] == segment end for node n

    // K1: h1bf = bf16(segsum(m, dst)) via gather
    k1_gather_h1<<<(N + 3) / 4, 256, 0, stream>>>(m, perm, off, cur, h1bf, N);

    // K2: A = h1 @ Wa^T + b0   (MFMA)
    gemm_mfma<false><<<ntA, 256, 0, stream>>>(h1bf, W0, 0, b0, nullptr, nullptr,
                                              A, nullptr, nullptr, N, ntA);

    // K3: x = m @ Wb^T + A[src]; stats; store bf16   (MFMA, persistent grid)
    gemm_mfma<true><<<2048, 256, 0, stream>>>(m, W0, 64, nullptr, A, src,
                                              nullptr, xbf, gs, E, ntE);

    // K4: scale/shift
    k4_finalize<<<1, 128, 0, stream>>>(gs, g0, beta0, sc, 1.0f / (float)E);

    // K5: out = segsum(relu(x*scale+shift), dst) via gather
    k5_gather_out<<<(N + 3) / 4, 256, 0, stream>>>(xbf, perm, off, cur, sc, out, N);
}